// Round 5
// baseline (240.490 us; speedup 1.0000x reference)
//
#include <hip/hip_runtime.h>
#include <stdint.h>

#define C_ITEMS 16384
#define NCLS 16
#define HSTRIDE 16386   // AP hist entries per class (opt in [1, P+1])
#define NB 16384        // negative sort buckets per class (ordkey >> 18)
#define BSH 18

// ---- workspace layout (bytes) ----
// col  [0,1M)  spos [1M,2M)  sneg [2M,3M)  aopt [3M,3M+32K)  hist+scalars [4M,~5.05M)
// ppk  [6M,8M)
static const size_t OFF_COL  = 0;                                     // 16*16384 f32 col-major scores
static const size_t OFF_SPOS = 1u << 20;                              // sorted positives (desc) per class
static const size_t OFF_SNEG = 2u << 20;                              // per-(class,rank) negative score (f32)
static const size_t OFF_AOPT = 3u << 20;                              // 16 * 512 u32 anchor opts (dead pack region)
static const size_t OFF_HIST = 4u << 20;                              // 16 * HSTRIDE u32 (AP hist)
static const size_t OFF_CNT  = OFF_HIST + (size_t)NCLS * HSTRIDE * 4; // done counter (u32) + pad  (= 5,243,008)
static const size_t OFF_ACCS = OFF_CNT + 64;                          // 16 double
static const size_t OFF_ACCV = OFF_ACCS + 128;                        // 16 double
static const size_t OFF_TOT  = OFF_ACCV + 128;                        // 1 double
static const size_t OFF_PC   = OFF_TOT + 8;                           // 16 u32 positive counters (= per-class P)
static const size_t ZERO_END = OFF_PC + 64;
static const size_t ZERO_BYTES = ZERO_END - OFF_HIST;                 // zero hist..pcnt (contiguous ~1.05 MB)
static const size_t OFF_PPK  = 6u << 20;                              // 16 * 16384 u64 positive keys
// NOTE: aopt region [3M, 3M+32K) must stay clear of sneg (ends exactly at 3M)
// and hist (starts at 4M). R4's bug: aopt at 5M overlapped hist tail + pcnt.

__device__ __forceinline__ unsigned ordkey(float f) {
  unsigned b = __float_as_uint(f);
  return (b & 0x80000000u) ? ~b : (b | 0x80000000u);   // monotone float->uint
}

__global__ void k_zero(unsigned* p, int n) {
  int stride = gridDim.x * blockDim.x;
  for (int t = blockIdx.x * blockDim.x + threadIdx.x; t < n; t += stride) p[t] = 0u;
}

// ---- fused transpose + positive collect (64 blocks x 256) ----
// Transpose: thread i reads row i (64 B, float4 x4, coalesced); for each class
// cc the 64 lanes write col[cc<<14 | i] at consecutive i -> coalesced 256 B.
// Positive collect: validated two-level reservation (<=1024 global atomics
// spread over 64 blocks). pcnt ends as per-class P.
__global__ void k_prep2(const float* __restrict__ scores, const int* __restrict__ labels,
                        float* __restrict__ col, unsigned* __restrict__ pcnt,
                        unsigned long long* __restrict__ ppk) {
  __shared__ unsigned lc[NCLS];
  __shared__ unsigned base[NCLS];
  int tid = threadIdx.x;
  if (tid < NCLS) lc[tid] = 0;
  __syncthreads();
  int i = blockIdx.x * 256 + tid;   // 0..16383
  const float4* rp = (const float4*)(scores + (size_t)i * NCLS);
  float4 r0 = rp[0], r1 = rp[1], r2 = rp[2], r3 = rp[3];
  int c = labels[i] & 15;
  unsigned loc = atomicAdd(&lc[c], 1u);
  __syncthreads();
  if (tid < NCLS) base[tid] = lc[tid] ? atomicAdd(&pcnt[tid], lc[tid]) : 0u;
  __syncthreads();
  float v = scores[(size_t)i * NCLS + c];   // L1-hot (row just loaded)
  ppk[(c << 14) + base[c] + loc] = ((unsigned long long)(~ordkey(v)) << 32) | (unsigned)i;
  col[(0 << 14) + i] = r0.x;  col[(1 << 14) + i] = r0.y;
  col[(2 << 14) + i] = r0.z;  col[(3 << 14) + i] = r0.w;
  col[(4 << 14) + i] = r1.x;  col[(5 << 14) + i] = r1.y;
  col[(6 << 14) + i] = r1.z;  col[(7 << 14) + i] = r1.w;
  col[(8 << 14) + i] = r2.x;  col[(9 << 14) + i] = r2.y;
  col[(10 << 14) + i] = r2.z; col[(11 << 14) + i] = r2.w;
  col[(12 << 14) + i] = r3.x; col[(13 << 14) + i] = r3.y;
  col[(14 << 14) + i] = r3.z; col[(15 << 14) + i] = r3.w;
}

// ============================================================================
// Per-class fused sort pipeline, one block per class, everything in LDS:
//   A: positive rank (O(P^2) count, pk staged in LDS)  -> spos + sp(LDS)
//   B: 16384-bucket LDS histogram of negatives (ordkey>>18)
//   C: exclusive scan (1024-thread ladder)
//   D: scatter (k<<14 | i): low-18 key bits + 14-bit idx = unique stable key
//   E: rankfine (bucket scan) -> sneg  (same (key,idx) total order as before)
//   F: anchors: exact serial backward suffix-argmax scans (bit-identical op
//      order to the validated k_anchor), sp from LDS.
// opt_j monotone non-increasing in j (the property the reference's quickselect
// D&C exploits) => anchors bracket all intermediate opts (consumed by k_optB).
// ============================================================================
#define SCAP 2048
#define ASTEP 64
#define ABITS 6

extern __shared__ char smem_ms[];

__global__ __launch_bounds__(1024) void k_megasort(
    const float* __restrict__ col, const int* __restrict__ labels,
    const unsigned* __restrict__ pcnt, const unsigned long long* __restrict__ ppk,
    float* __restrict__ spos, float* __restrict__ sneg, unsigned* __restrict__ aopt) {
  int c = blockIdx.x;
  int tid = threadIdx.x;
  int P = (int)pcnt[c];
  int N = C_ITEMS - P;
  unsigned* hist = (unsigned*)smem_ms;                       // [NB]    64 KB
  unsigned* pack = (unsigned*)(smem_ms + (size_t)NB * 4);    // [16384] 64 KB
  float*    sp   = (float*)(smem_ms + (size_t)NB * 4 + 65536); // [2048] 8 KB
  unsigned long long* pk = (unsigned long long*)pack;        // alias (phase A only)
  __shared__ unsigned part[1024];

  // ---- phase A: positives ----
  bool small = (P > 0 && P <= SCAP);
  if (small) {
    const unsigned long long* src = ppk + ((size_t)c << 14);
    for (int t = tid; t < P; t += 1024) pk[t] = src[t];
    __syncthreads();
    for (int q = tid; q < P; q += 1024) {
      unsigned long long k64 = pk[q];
      unsigned cq = 0;
      for (int t = 0; t < P; ++t) cq += (pk[t] < k64) ? 1u : 0u;
      unsigned i = (unsigned)(k64 & 0xFFFFFFFFu);
      float v = col[(c << 14) + (int)i];
      sp[cq] = v;
      spos[(c << 14) + (int)cq] = v;
    }
  } else if (P > 0) {  // safety fallback (won't trigger for this input)
    const unsigned long long* src = ppk + ((size_t)c << 14);
    for (int q = tid; q < P; q += 1024) {
      unsigned long long k64 = src[q];
      unsigned cq = 0;
      for (int t = 0; t < P; ++t) cq += (src[t] < k64) ? 1u : 0u;
      unsigned i = (unsigned)(k64 & 0xFFFFFFFFu);
      spos[(c << 14) + (int)cq] = col[(c << 14) + (int)i];
    }
  }
  __syncthreads();   // pk (pack alias) dead past here

  // ---- phase B: bucket histogram ----
  for (int b = tid; b < NB; b += 1024) hist[b] = 0u;
  __syncthreads();
  if (N > 0)
    for (int i = tid; i < C_ITEMS; i += 1024)
      if (labels[i] != c) atomicAdd(&hist[ordkey(col[(c << 14) + i]) >> BSH], 1u);
  __syncthreads();

  // ---- phase C: exclusive scan over NB buckets ----
  {
    int base = tid * (NB / 1024);
    unsigned s = 0;
    for (int q = 0; q < NB / 1024; ++q) s += hist[base + q];
    part[tid] = s;
    __syncthreads();
    for (int off = 1; off < 1024; off <<= 1) {
      unsigned v = (tid >= off) ? part[tid - off] : 0u;
      __syncthreads();
      part[tid] += v;
      __syncthreads();
    }
    unsigned running = part[tid] - s;
    for (int q = 0; q < NB / 1024; ++q) {
      unsigned tmp = hist[base + q];
      hist[base + q] = running;
      running += tmp;
    }
  }
  __syncthreads();

  // ---- phase D: scatter (hist[b] becomes bucket END) ----
  if (N > 0)
    for (int i = tid; i < C_ITEMS; i += 1024)
      if (labels[i] != c) {
        unsigned k = ordkey(col[(c << 14) + i]);
        unsigned p = atomicAdd(&hist[k >> BSH], 1u);
        pack[p] = (k << 14) | (unsigned)i;
      }
  __syncthreads();

  // ---- phase E: rankfine -> sneg (cnt = unique 0-based ascending rank) ----
  if (N > 0)
    for (int i = tid; i < C_ITEMS; i += 1024)
      if (labels[i] != c) {
        float v = col[(c << 14) + i];
        unsigned k = ordkey(v);
        unsigned b = k >> BSH;
        unsigned start = b ? hist[b - 1] : 0u;
        unsigned end = hist[b];
        unsigned mine = (k << 14) | (unsigned)i;
        unsigned cnt = start;
        for (unsigned q = start; q < end; ++q) cnt += (pack[q] < mine) ? 1u : 0u;
        sneg[(c << 14) + (int)cnt] = v;
      }
  __threadfence_block();
  __syncthreads();   // sneg visible to this block (write-through L1 -> L2)

  // ---- phase F: anchors ----
  if (P > 0 && N > 0) {
    int T = (N + ASTEP - 1) / ASTEP + 1;
    float invP = 1.0f / (float)P;
    float coef = 2.0f / ((float)P * (float)N);
    for (int t = tid; t < T; t += 1024) {
      int j0 = min(t * ASTEP, N - 1);
      float v = sneg[(c << 14) + j0];
      float a = coef * v;
      float fcnt = (float)(j0 + P + 1);
      float s = 0.0f, best = 0.0f;
      int besti = P;
      if (P <= SCAP) {
        for (int q = P - 1; q >= 0; --q) {
          float spv = sp[q];
          float r = __builtin_amdgcn_rcpf(fcnt);
          float delta = fmaf(invP, r, fmaf(-coef, spv, a));
          s += delta;
          if (s >= best) { best = s; besti = q; }
          fcnt -= 1.0f;
        }
      } else {
        const float* spg = spos + ((size_t)c << 14);
        for (int q = P - 1; q >= 0; --q) {
          float spv = spg[q];
          float r = __builtin_amdgcn_rcpf(fcnt);
          float delta = fmaf(invP, r, fmaf(-coef, spv, a));
          s += delta;
          if (s >= best) { best = s; besti = q; }
          fcnt -= 1.0f;
        }
      }
      aopt[(c << 9) + t] = (unsigned)(besti + 1);
    }
  }
}

// ---- bracketed per-negative argmax + histogram + minus-side sums ----
#define HCAP 2048
__global__ void k_optB(const unsigned* __restrict__ counts, const float* __restrict__ spos,
                       const float* __restrict__ sneg, const unsigned* __restrict__ aopt,
                       unsigned* __restrict__ hist, double* __restrict__ accS,
                       double* __restrict__ accV) {
  int c = blockIdx.y;
  int P = (int)counts[c];
  int N = C_ITEMS - P;
  if (P == 0 || N == 0) return;
  int tid = threadIdx.x;
  int j0 = blockIdx.x * 256 + tid;
  bool active = (j0 < N);
  __shared__ float sp[SCAP];
  __shared__ unsigned lh[HCAP];
  __shared__ double red[256];
  int stageN = (P <= SCAP) ? P : 0;
  for (int t = tid; t < stageN; t += 256) sp[t] = spos[(c << 14) + t];
  for (int t = tid; t < HCAP; t += 256) lh[t] = 0u;
  __syncthreads();
  int opt = P + 1;
  float v = 0.0f;
  if (active) {
    v = sneg[(c << 14) + j0];
    int g = j0 >> ABITS;
    int hiA = (int)aopt[(c << 9) + g];
    if ((j0 & (ASTEP - 1)) == 0) {
      opt = hiA;                      // anchor rank: exact full-scan value
    } else {
      int loA = (int)aopt[(c << 9) + g + 1];
      int hi = min(hiA + 2, P + 1);   // +-2 margin absorbs float near-tie wobble
      int lo = max(loA - 2, 1);
      float invP = 1.0f / (float)P;
      float coef = 2.0f / ((float)P * (float)N);
      float a = coef * v;
      float s = 0.0f, best = 0.0f;
      int bestr = hi;                 // empty suffix (value 0) candidate at r=hi
      float fcnt = (float)(j0 + hi);  // j0+1+k at k=hi-1
      if (P <= SCAP) {
        for (int k = hi - 1; k >= lo; --k) {
          float spv = sp[k - 1];
          float r = __builtin_amdgcn_rcpf(fcnt);
          float delta = fmaf(invP, r, fmaf(-coef, spv, a));
          s += delta;
          if (s >= best) { best = s; bestr = k; }
          fcnt -= 1.0f;
        }
      } else {
        const float* spg = spos + ((size_t)c << 14);
        for (int k = hi - 1; k >= lo; --k) {
          float spv = spg[k - 1];
          float r = __builtin_amdgcn_rcpf(fcnt);
          float delta = fmaf(invP, r, fmaf(-coef, spv, a));
          s += delta;
          if (s >= best) { best = s; bestr = k; }
          fcnt -= 1.0f;
        }
      }
      opt = bestr;
    }
  }
  if (P + 2 <= HCAP) {
    if (active) atomicAdd(&lh[opt], 1u);
    __syncthreads();
    for (int t = tid; t < P + 2; t += 256)
      if (lh[t]) atomicAdd(&hist[c * HSTRIDE + t], lh[t]);
  } else {
    if (active) atomicAdd(&hist[c * HSTRIDE + opt], 1u);
  }
  double cm = active ? (double)(P + 2 - 2 * opt) * (double)v : 0.0;
  double sv = active ? (double)v : 0.0;
  red[tid] = cm; __syncthreads();
  for (int sh = 128; sh > 0; sh >>= 1) { if (tid < sh) red[tid] += red[tid + sh]; __syncthreads(); }
  if (tid == 0) atomicAdd(&accS[c], red[0]);
  __syncthreads();
  red[tid] = sv; __syncthreads();
  for (int sh = 128; sh > 0; sh >>= 1) { if (tid < sh) red[tid] += red[tid + sh]; __syncthreads(); }
  if (tid == 0) atomicAdd(&accV[c], red[0]);
}

// ---- per-class: prefix-sum hist -> r_plus, plus-side sums, loss, final out ----
// Last-finishing block (done-counter protocol) writes out; all blocks reach the
// protocol even when P==0||N==0.
__global__ void k_fin(const unsigned* __restrict__ counts, const unsigned* __restrict__ hist,
                      const float* __restrict__ spos, const double* __restrict__ accS,
                      const double* __restrict__ accV, double* __restrict__ total,
                      unsigned* __restrict__ done, float* __restrict__ out) {
  int c = blockIdx.x;
  int tid = threadIdx.x;
  int P = (int)counts[c];
  int N = C_ITEMS - P;
  __shared__ unsigned sc[256];
  __shared__ double red[256];
  double lc = 0.0;
  if (P > 0 && N > 0) {
    const unsigned* h = hist + c * HSTRIDE;
    int M = P + 1;
    int L = (M + 255) / 256;
    int o0 = 1 + tid * L;
    int o1 = min(o0 + L, P + 2);
    unsigned part = 0;
    for (int o = o0; o < o1; ++o) part += h[o];
    sc[tid] = part;
    __syncthreads();
    if (tid == 0) {
      unsigned runp = 0;
      for (int t = 0; t < 256; ++t) { unsigned tmp = sc[t]; sc[t] = runp; runp += tmp; }
    }
    __syncthreads();
    unsigned run = sc[tid];
    double a1 = 0.0, a2 = 0.0, a3 = 0.0;
    for (int o = o0; o < o1; ++o) {
      run += h[o];
      if (o <= P) {
        int k0 = o - 1;
        double rp = 1.0 + (double)run;
        double spv = (double)spos[(c << 14) + k0];
        a1 += (double)(k0 + 1) / ((double)k0 + rp);
        a2 += spv * ((double)N + 2.0 - 2.0 * rp);
        a3 += spv;
      }
    }
    red[tid] = a1; __syncthreads();
    for (int s = 128; s > 0; s >>= 1) { if (tid < s) red[tid] += red[tid + s]; __syncthreads(); }
    double r1 = red[0]; __syncthreads();
    red[tid] = a2; __syncthreads();
    for (int s = 128; s > 0; s >>= 1) { if (tid < s) red[tid] += red[tid + s]; __syncthreads(); }
    double r2 = red[0]; __syncthreads();
    red[tid] = a3; __syncthreads();
    for (int s = 128; s > 0; s >>= 1) { if (tid < s) red[tid] += red[tid + s]; __syncthreads(); }
    double r3 = red[0];
    if (tid == 0) {
      double Pd = (double)P, Nd = (double)N;
      double FR  = r2 + accS[c];
      double FRs = Nd * r3 - Pd * accV[c];
      lc = (1.0 - r1 / Pd) + (FR - FRs) / (Pd * Nd);
    }
  }
  if (tid == 0) {
    if (P > 0 && N > 0) atomicAdd(total, lc);
    __threadfence();
    unsigned d = atomicAdd(done, 1u);
    if (d == NCLS - 1) {
      double t = atomicAdd(total, 0.0);  // device-scope RMW: coherent final value
      out[0] = (float)(t / (double)NCLS);
    }
  }
}

extern "C" void kernel_launch(void* const* d_in, const int* in_sizes, int n_in,
                              void* d_out, int out_size, void* d_ws, size_t ws_size,
                              hipStream_t stream) {
  (void)in_sizes; (void)n_in; (void)out_size; (void)ws_size;
  const float* scores = (const float*)d_in[0];
  const int* labels = (const int*)d_in[1];
  float* out = (float*)d_out;
  char* ws = (char*)d_ws;
  float* col      = (float*)(ws + OFF_COL);
  float* spos     = (float*)(ws + OFF_SPOS);
  float* sneg     = (float*)(ws + OFF_SNEG);
  unsigned* aopt  = (unsigned*)(ws + OFF_AOPT);
  unsigned* hist  = (unsigned*)(ws + OFF_HIST);
  unsigned* done  = (unsigned*)(ws + OFF_CNT);
  double* accS    = (double*)(ws + OFF_ACCS);
  double* accV    = (double*)(ws + OFF_ACCV);
  double* total   = (double*)(ws + OFF_TOT);
  unsigned* pcnt  = (unsigned*)(ws + OFF_PC);   // per-class P counts
  unsigned long long* ppk = (unsigned long long*)(ws + OFF_PPK);

  size_t msLds = (size_t)NB * 4 + 65536 + 8192;   // hist + pack + sp = 136 KB
  static bool attr_done = false;
  if (!attr_done) {   // defensive opt-in for >64KB dynamic LDS; no-op/ignored on ROCm
    (void)hipFuncSetAttribute((const void*)k_megasort,
                              hipFuncAttributeMaxDynamicSharedMemorySize, (int)msLds);
    attr_done = true;
  }

  int zn = (int)(ZERO_BYTES / 4);
  k_zero<<<256, 256, 0, stream>>>(hist, zn);      // zeroes hist..pcnt (contiguous)
  k_prep2<<<64, 256, 0, stream>>>(scores, labels, col, pcnt, ppk);
  k_megasort<<<NCLS, 1024, msLds, stream>>>(col, labels, pcnt, ppk, spos, sneg, aopt);
  k_optB<<<dim3(64, NCLS), 256, 0, stream>>>(pcnt, spos, sneg, aopt, hist, accS, accV);
  k_fin<<<NCLS, 256, 0, stream>>>(pcnt, hist, spos, accS, accV, total, done, out);
}

// Round 6
// 237.026 us; speedup vs baseline: 1.0146x; 1.0146x over previous
//
#include <hip/hip_runtime.h>
#include <stdint.h>

#define C_ITEMS 16384
#define NCLS 16
#define HSTRIDE 16386   // AP hist entries per class (opt in [1, P+1])
#define NB 16384        // negative sort buckets per class (ordkey >> 18)
#define BSH 18

// ---- workspace layout (bytes) ----
// col[0,1M) spos[1M,2M) sneg[2M,3M) pack[3M,4M) hist+scalars+h1[4M,~6.3M) ppk[6.5M,8.5M)
static const size_t OFF_COL  = 0;                                     // 16*16384 f32 col-major scores
static const size_t OFF_SPOS = 1u << 20;                              // sorted positives (desc) per class
static const size_t OFF_SNEG = 2u << 20;                              // per-(class,rank) negative score
static const size_t OFF_PACK = 3u << 20;                              // bucket-scattered (low18key,idx14)
static const size_t OFF_HIST = 4u << 20;                              // 16 * HSTRIDE u32 (AP hist)
static const size_t OFF_CNT  = OFF_HIST + (size_t)NCLS * HSTRIDE * 4; // done counter (u32) + pad
static const size_t OFF_ACCS = OFF_CNT + 64;                          // 16 double
static const size_t OFF_ACCV = OFF_ACCS + 128;                        // 16 double
static const size_t OFF_TOT  = OFF_ACCV + 128;                        // 1 double
static const size_t OFF_PC   = OFF_TOT + 8;                           // 16 u32 positive counters (= per-class P)
static const size_t OFF_H1   = (OFF_PC + 64 + 255) & ~(size_t)255;    // 16 * 16384 u32 bucket hist (1 MB)
static const size_t ZERO_END = OFF_H1 + ((size_t)NCLS * NB * 4);
static const size_t ZERO_BYTES = ZERO_END - OFF_HIST;                 // ~2.1 MB contiguous
static const size_t OFF_PPK  = 6656u << 10;                           // 6.5M: 16 * 16384 u64 positive keys
// aopt (16*512 u32 = 32 KB) aliases OFF_PPK: written by k_anchor strictly after
// k_mid consumed ppk (stream-ordered). R4 lesson: verify no live-region overlap.

__device__ __forceinline__ unsigned ordkey(float f) {
  unsigned b = __float_as_uint(f);
  return (b & 0x80000000u) ? ~b : (b | 0x80000000u);   // monotone float->uint
}

__global__ void k_zero(unsigned* __restrict__ p, int n) {
  int stride = gridDim.x * blockDim.x;
  for (int t = blockIdx.x * blockDim.x + threadIdx.x; t < n; t += stride) p[t] = 0u;
}

// ---- fused transpose + positive collect + negative bucket histogram ----
// (64 blocks x 256). Row i in registers; per class cc: coalesced col store and
// (if negative) one fire-and-forget atomic into the 16K-bucket class histogram.
// Positive collect: validated two-level reservation; pcnt ends as per-class P.
__global__ void k_prep2(const float* __restrict__ scores, const int* __restrict__ labels,
                        float* __restrict__ col, unsigned* __restrict__ pcnt,
                        unsigned long long* __restrict__ ppk, unsigned* __restrict__ h1) {
  __shared__ unsigned lc[NCLS];
  __shared__ unsigned base[NCLS];
  int tid = threadIdx.x;
  if (tid < NCLS) lc[tid] = 0;
  __syncthreads();
  int i = blockIdx.x * 256 + tid;   // 0..16383
  const float4* rp = (const float4*)(scores + (size_t)i * NCLS);
  float4 r0 = rp[0], r1 = rp[1], r2 = rp[2], r3 = rp[3];
  float vals[16] = {r0.x, r0.y, r0.z, r0.w, r1.x, r1.y, r1.z, r1.w,
                    r2.x, r2.y, r2.z, r2.w, r3.x, r3.y, r3.z, r3.w};
  int c = labels[i] & 15;
  unsigned loc = atomicAdd(&lc[c], 1u);
  __syncthreads();
  if (tid < NCLS) base[tid] = lc[tid] ? atomicAdd(&pcnt[tid], lc[tid]) : 0u;
  __syncthreads();
  float v = vals[c];
  ppk[(c << 14) + base[c] + loc] = ((unsigned long long)(~ordkey(v)) << 32) | (unsigned)i;
#pragma unroll
  for (int cc = 0; cc < NCLS; ++cc) {
    col[(cc << 14) + i] = vals[cc];
    if (cc != c) atomicAdd(&h1[(cc << 14) + (ordkey(vals[cc]) >> BSH)], 1u);
  }
}

// ---- wide merged kernel: blocks 0-15 = per-class 16K-bucket exclusive scan;
//      blocks 16-79 = positive rank (4 blocks/class, 256 active thr each) ----
#define PCAP 2048
__global__ void k_mid(unsigned* __restrict__ h1, const float* __restrict__ col,
                      const unsigned* __restrict__ pcnt,
                      const unsigned long long* __restrict__ ppk,
                      float* __restrict__ spos) {
  int b = blockIdx.x;
  int tid = threadIdx.x;
  if (b < NCLS) {
    // exclusive prefix over NB buckets, 256 threads x 64 buckets each
    unsigned* h = h1 + ((size_t)b << 14);
    __shared__ unsigned part[256];
    unsigned base = (unsigned)tid << 6;
    unsigned s = 0;
    for (int q = 0; q < 64; ++q) s += h[base + q];
    part[tid] = s;
    __syncthreads();
    for (int off = 1; off < 256; off <<= 1) {
      unsigned v = (tid >= off) ? part[tid - off] : 0u;
      __syncthreads();
      part[tid] += v;
      __syncthreads();
    }
    unsigned running = part[tid] - s;
    for (int q = 0; q < 64; ++q) {
      unsigned tmp = h[base + q];
      h[base + q] = running;
      running += tmp;
    }
  } else {
    // positive rank: keys unique -> count-smaller is permutation-invariant
    int c = (b - NCLS) >> 2, s4 = (b - NCLS) & 3;
    unsigned P = pcnt[c];
    __shared__ unsigned long long pk[PCAP];
    const unsigned long long* src = ppk + ((size_t)c << 14);
    if (P <= PCAP) {
      for (unsigned t = tid; t < P; t += 256) pk[t] = src[t];
      __syncthreads();
      for (unsigned q = (unsigned)((tid << 2) + s4); q < P; q += 1024) {
        unsigned long long k64 = pk[q];
        unsigned cq = 0;
        for (unsigned t = 0; t < P; ++t) cq += (pk[t] < k64) ? 1u : 0u;
        unsigned i = (unsigned)(k64 & 0xFFFFFFFFu);
        spos[(c << 14) + cq] = col[(c << 14) + (int)i];
      }
    } else {  // safety fallback (won't trigger for this input)
      for (unsigned q = (unsigned)((tid << 2) + s4); q < P; q += 1024) {
        unsigned long long k64 = src[q];
        unsigned cq = 0;
        for (unsigned t = 0; t < P; ++t) cq += (src[t] < k64) ? 1u : 0u;
        unsigned i = (unsigned)(k64 & 0xFFFFFFFFu);
        spos[(c << 14) + cq] = col[(c << 14) + (int)i];
      }
    }
  }
}

// ---- scatter negatives into bucket-grouped array; h1[b] becomes bucket END ----
__global__ void k_scatter(const float* __restrict__ col, const int* __restrict__ labels,
                          unsigned* __restrict__ h1, unsigned* __restrict__ pack) {
  int t = blockIdx.x * 256 + threadIdx.x;
  int c = t >> 14, i = t & 16383;
  if (labels[i] != c) {
    unsigned k = ordkey(col[t]);
    unsigned p = atomicAdd(&h1[(c << 14) + (k >> BSH)], 1u);
    pack[(c << 14) + p] = (k << 14) | (unsigned)i;   // low-18 key bits + idx: unique
  }
}

// ---- final rank (bucket start + count-smaller in bucket) -> sneg by rank ----
__global__ void k_rankfine(const float* __restrict__ col, const int* __restrict__ labels,
                           const unsigned* __restrict__ h1, const unsigned* __restrict__ pack,
                           float* __restrict__ sneg) {
  int t = blockIdx.x * 256 + threadIdx.x;
  int c = t >> 14, i = t & 16383;
  if (labels[i] != c) {
    float v = col[t];
    unsigned k = ordkey(v);
    unsigned b = k >> BSH;
    const unsigned* hb = h1 + ((size_t)c << 14);
    unsigned start = b ? hb[b - 1] : 0u;   // after scatter: hb[x] = end of bucket x
    unsigned end = hb[b];
    unsigned mine = (k << 14) | (unsigned)i;
    const unsigned* pk = pack + (c << 14);
    unsigned cnt = start;
    for (unsigned q = start; q < end; ++q) cnt += (pk[q] < mine) ? 1u : 0u;
    sneg[(c << 14) + (int)cnt] = v;        // cnt = 0-based ascending rank (unique)
  }
}

// ============================================================================
// opt_j monotone non-increasing in ascending rank j (the property the
// reference's quickselect D&C exploits) => anchors every ASTEP ranks bracket
// every intermediate opt. Anchor math is the exact validated serial scan.
// ============================================================================
#define SCAP 2048
#define ASTEP 64
#define ABITS 6

// one thread per anchor, 64-thr blocks, grid (5, NCLS): 320 slots >= T<=257
__global__ void k_anchor(const unsigned* __restrict__ counts, const float* __restrict__ spos,
                         const float* __restrict__ sneg, unsigned* __restrict__ aopt) {
  int c = blockIdx.y;
  int P = (int)counts[c];
  int N = C_ITEMS - P;
  if (P == 0 || N == 0) return;
  int tid = threadIdx.x;
  __shared__ float sp[SCAP];
  int stageN = (P <= SCAP) ? P : 0;
  for (int t = tid; t < stageN; t += 64) sp[t] = spos[(c << 14) + t];
  __syncthreads();
  int ta = blockIdx.x * 64 + tid;
  int T = (N + ASTEP - 1) / ASTEP + 1;      // full anchors + terminal anchor at N-1
  if (ta >= T) return;
  float invP = 1.0f / (float)P;
  float coef = 2.0f / ((float)P * (float)N);
  int j0 = min(ta * ASTEP, N - 1);
  float v = sneg[(c << 14) + j0];
  float a = coef * v;
  float fcnt = (float)(j0 + P + 1);
  float s = 0.0f, best = 0.0f;
  int besti = P;
  if (P <= SCAP) {
    for (int q = P - 1; q >= 0; --q) {
      float spv = sp[q];
      float r = __builtin_amdgcn_rcpf(fcnt);
      float delta = fmaf(invP, r, fmaf(-coef, spv, a));
      s += delta;
      if (s >= best) { best = s; besti = q; }
      fcnt -= 1.0f;
    }
  } else {
    const float* spg = spos + ((size_t)c << 14);
    for (int q = P - 1; q >= 0; --q) {
      float spv = spg[q];
      float r = __builtin_amdgcn_rcpf(fcnt);
      float delta = fmaf(invP, r, fmaf(-coef, spv, a));
      s += delta;
      if (s >= best) { best = s; besti = q; }
      fcnt -= 1.0f;
    }
  }
  aopt[(c << 9) + ta] = (unsigned)(besti + 1);
}

// ---- bracketed per-negative argmax + histogram + minus-side sums ----
#define HCAP 2048
__global__ void k_optB(const unsigned* __restrict__ counts, const float* __restrict__ spos,
                       const float* __restrict__ sneg, const unsigned* __restrict__ aopt,
                       unsigned* __restrict__ hist, double* __restrict__ accS,
                       double* __restrict__ accV) {
  int c = blockIdx.y;
  int P = (int)counts[c];
  int N = C_ITEMS - P;
  if (P == 0 || N == 0) return;
  int tid = threadIdx.x;
  int j0 = blockIdx.x * 256 + tid;
  bool active = (j0 < N);
  __shared__ float sp[SCAP];
  __shared__ unsigned lh[HCAP];
  __shared__ double red[256];
  int stageN = (P <= SCAP) ? P : 0;
  int zn = (P + 2 <= HCAP) ? (P + 2) : 0;
  for (int t = tid; t < stageN; t += 256) sp[t] = spos[(c << 14) + t];
  for (int t = tid; t < zn; t += 256) lh[t] = 0u;
  __syncthreads();
  int opt = P + 1;
  float v = 0.0f;
  if (active) {
    v = sneg[(c << 14) + j0];
    int g = j0 >> ABITS;
    int hiA = (int)aopt[(c << 9) + g];
    if ((j0 & (ASTEP - 1)) == 0) {
      opt = hiA;                      // anchor rank: exact full-scan value
    } else {
      int loA = (int)aopt[(c << 9) + g + 1];
      int hi = min(hiA + 2, P + 1);   // +-2 margin absorbs float near-tie wobble
      int lo = max(loA - 2, 1);
      float invP = 1.0f / (float)P;
      float coef = 2.0f / ((float)P * (float)N);
      float a = coef * v;
      float s = 0.0f, best = 0.0f;
      int bestr = hi;                 // empty suffix (value 0) candidate at r=hi
      float fcnt = (float)(j0 + hi);  // j0+1+k at k=hi-1
      if (P <= SCAP) {
        for (int k = hi - 1; k >= lo; --k) {
          float spv = sp[k - 1];
          float r = __builtin_amdgcn_rcpf(fcnt);
          float delta = fmaf(invP, r, fmaf(-coef, spv, a));
          s += delta;
          if (s >= best) { best = s; bestr = k; }
          fcnt -= 1.0f;
        }
      } else {
        const float* spg = spos + ((size_t)c << 14);
        for (int k = hi - 1; k >= lo; --k) {
          float spv = spg[k - 1];
          float r = __builtin_amdgcn_rcpf(fcnt);
          float delta = fmaf(invP, r, fmaf(-coef, spv, a));
          s += delta;
          if (s >= best) { best = s; bestr = k; }
          fcnt -= 1.0f;
        }
      }
      opt = bestr;
    }
  }
  if (P + 2 <= HCAP) {
    if (active) atomicAdd(&lh[opt], 1u);
    __syncthreads();
    for (int t = tid; t < P + 2; t += 256)
      if (lh[t]) atomicAdd(&hist[c * HSTRIDE + t], lh[t]);
  } else {
    if (active) atomicAdd(&hist[c * HSTRIDE + opt], 1u);
  }
  double cm = active ? (double)(P + 2 - 2 * opt) * (double)v : 0.0;
  double sv = active ? (double)v : 0.0;
  red[tid] = cm; __syncthreads();
  for (int sh = 128; sh > 0; sh >>= 1) { if (tid < sh) red[tid] += red[tid + sh]; __syncthreads(); }
  if (tid == 0) atomicAdd(&accS[c], red[0]);
  __syncthreads();
  red[tid] = sv; __syncthreads();
  for (int sh = 128; sh > 0; sh >>= 1) { if (tid < sh) red[tid] += red[tid + sh]; __syncthreads(); }
  if (tid == 0) atomicAdd(&accV[c], red[0]);
}

// ---- per-class: prefix-sum hist -> r_plus, plus-side sums, loss, final out ----
__global__ void k_fin(const unsigned* __restrict__ counts, const unsigned* __restrict__ hist,
                      const float* __restrict__ spos, const double* __restrict__ accS,
                      const double* __restrict__ accV, double* __restrict__ total,
                      unsigned* __restrict__ done, float* __restrict__ out) {
  int c = blockIdx.x;
  int tid = threadIdx.x;
  int P = (int)counts[c];
  int N = C_ITEMS - P;
  __shared__ unsigned sc[256];
  __shared__ double red[256];
  double lc = 0.0;
  if (P > 0 && N > 0) {
    const unsigned* h = hist + c * HSTRIDE;
    int M = P + 1;
    int L = (M + 255) / 256;
    int o0 = 1 + tid * L;
    int o1 = min(o0 + L, P + 2);
    unsigned part = 0;
    for (int o = o0; o < o1; ++o) part += h[o];
    sc[tid] = part;
    __syncthreads();
    if (tid == 0) {
      unsigned runp = 0;
      for (int t = 0; t < 256; ++t) { unsigned tmp = sc[t]; sc[t] = runp; runp += tmp; }
    }
    __syncthreads();
    unsigned run = sc[tid];
    double a1 = 0.0, a2 = 0.0, a3 = 0.0;
    for (int o = o0; o < o1; ++o) {
      run += h[o];
      if (o <= P) {
        int k0 = o - 1;
        double rp = 1.0 + (double)run;
        double spv = (double)spos[(c << 14) + k0];
        a1 += (double)(k0 + 1) / ((double)k0 + rp);
        a2 += spv * ((double)N + 2.0 - 2.0 * rp);
        a3 += spv;
      }
    }
    red[tid] = a1; __syncthreads();
    for (int s = 128; s > 0; s >>= 1) { if (tid < s) red[tid] += red[tid + s]; __syncthreads(); }
    double r1 = red[0]; __syncthreads();
    red[tid] = a2; __syncthreads();
    for (int s = 128; s > 0; s >>= 1) { if (tid < s) red[tid] += red[tid + s]; __syncthreads(); }
    double r2 = red[0]; __syncthreads();
    red[tid] = a3; __syncthreads();
    for (int s = 128; s > 0; s >>= 1) { if (tid < s) red[tid] += red[tid + s]; __syncthreads(); }
    double r3 = red[0];
    if (tid == 0) {
      double Pd = (double)P, Nd = (double)N;
      double FR  = r2 + accS[c];
      double FRs = Nd * r3 - Pd * accV[c];
      lc = (1.0 - r1 / Pd) + (FR - FRs) / (Pd * Nd);
    }
  }
  if (tid == 0) {
    if (P > 0 && N > 0) atomicAdd(total, lc);
    __threadfence();
    unsigned d = atomicAdd(done, 1u);
    if (d == NCLS - 1) {
      double t = atomicAdd(total, 0.0);  // device-scope RMW: coherent final value
      out[0] = (float)(t / (double)NCLS);
    }
  }
}

extern "C" void kernel_launch(void* const* d_in, const int* in_sizes, int n_in,
                              void* d_out, int out_size, void* d_ws, size_t ws_size,
                              hipStream_t stream) {
  (void)in_sizes; (void)n_in; (void)out_size; (void)ws_size;
  const float* scores = (const float*)d_in[0];
  const int* labels = (const int*)d_in[1];
  float* out = (float*)d_out;
  char* ws = (char*)d_ws;
  float* col      = (float*)(ws + OFF_COL);
  float* spos     = (float*)(ws + OFF_SPOS);
  float* sneg     = (float*)(ws + OFF_SNEG);
  unsigned* pack  = (unsigned*)(ws + OFF_PACK);
  unsigned* hist  = (unsigned*)(ws + OFF_HIST);
  unsigned* done  = (unsigned*)(ws + OFF_CNT);
  double* accS    = (double*)(ws + OFF_ACCS);
  double* accV    = (double*)(ws + OFF_ACCV);
  double* total   = (double*)(ws + OFF_TOT);
  unsigned* pcnt  = (unsigned*)(ws + OFF_PC);   // per-class P counts
  unsigned* h1    = (unsigned*)(ws + OFF_H1);
  unsigned long long* ppk = (unsigned long long*)(ws + OFF_PPK);
  unsigned* aopt  = (unsigned*)(ws + OFF_PPK);  // reused after k_mid consumed ppk

  int zn = (int)(ZERO_BYTES / 4);
  k_zero<<<512, 256, 0, stream>>>(hist, zn);    // zeroes hist..h1 (contiguous 2.1 MB)
  k_prep2<<<64, 256, 0, stream>>>(scores, labels, col, pcnt, ppk, h1);
  k_mid<<<80, 256, 0, stream>>>(h1, col, pcnt, ppk, spos);
  k_scatter<<<1024, 256, 0, stream>>>(col, labels, h1, pack);
  k_rankfine<<<1024, 256, 0, stream>>>(col, labels, h1, pack, sneg);
  k_anchor<<<dim3(5, NCLS), 64, 0, stream>>>(pcnt, spos, sneg, aopt);
  k_optB<<<dim3(64, NCLS), 256, 0, stream>>>(pcnt, spos, sneg, aopt, hist, accS, accV);
  k_fin<<<NCLS, 256, 0, stream>>>(pcnt, hist, spos, accS, accV, total, done, out);
}

// Round 9
// 199.215 us; speedup vs baseline: 1.2072x; 1.1898x over previous
//
#include <hip/hip_runtime.h>
#include <stdint.h>

#define C_ITEMS 16384
#define NCLS 16
#define HSTRIDE 16386   // AP hist entries per class (opt in [1, P+1])
#define NB 65536        // negative sort buckets per class (ordkey >> 16)
#define BSH 16

// ---- workspace layout (bytes) ----
// col[0,1M) spos[1M,2M) sneg[2M,3M) pack[3M,4M) hist+scalars+h1[4M,~9.44M) ppk[10M,12M)
static const size_t OFF_COL  = 0;                                     // 16*16384 f32 col-major scores
static const size_t OFF_SPOS = 1u << 20;                              // sorted positives (desc) per class
static const size_t OFF_SNEG = 2u << 20;                              // per-(class,rank) negative score
static const size_t OFF_PACK = 3u << 20;                              // bucket-scattered (low16key,idx)
static const size_t OFF_HIST = 4u << 20;                              // 16 * HSTRIDE u32 (AP hist)
static const size_t OFF_CNT  = OFF_HIST + (size_t)NCLS * HSTRIDE * 4; // done counter (u32) + pad
static const size_t OFF_ACCS = OFF_CNT + 64;                          // 16 double
static const size_t OFF_ACCV = OFF_ACCS + 128;                        // 16 double
static const size_t OFF_TOT  = OFF_ACCV + 128;                        // 1 double
static const size_t OFF_PC   = OFF_TOT + 8;                           // 16 u32 positive counters (= per-class P)
static const size_t OFF_H1   = (OFF_PC + 64 + 255) & ~(size_t)255;    // 16 * 65536 u32 bucket hist (4 MB)
static const size_t ZERO_END = OFF_H1 + ((size_t)NCLS * NB * 4);
static const size_t ZERO_BYTES = ZERO_END - OFF_HIST;                 // ~5.25 MB contiguous
static const size_t OFF_PPK  = 10u << 20;                             // 16 * 16384 u64 positive keys
// aopt (16*512 u32 = 32 KB) aliases OFF_PPK: written by k_anchor strictly after
// k_mid consumed ppk (stream-ordered). R4 lesson: verify no live-region overlap.

__device__ __forceinline__ unsigned ordkey(float f) {
  unsigned b = __float_as_uint(f);
  return (b & 0x80000000u) ? ~b : (b | 0x80000000u);   // monotone float->uint
}

__global__ void k_zero(unsigned* __restrict__ p, int n) {
  int stride = gridDim.x * blockDim.x;
  for (int t = blockIdx.x * blockDim.x + threadIdx.x; t < n; t += stride) p[t] = 0u;
}

// ---- transpose + per-class negative bucket histogram (WIDE: 1024 blocks) ----
// One thread per (item,class) pair; scores load fully coalesced; 64K buckets
// keep hot-bucket atomic serialization ~4x lower than 16K (R6 regression).
__global__ void k_prep(const float* __restrict__ scores, const int* __restrict__ labels,
                       float* __restrict__ col, unsigned* __restrict__ h1) {
  int t = blockIdx.x * 256 + threadIdx.x;      // 0..262143
  float v = scores[t];
  int i = t >> 4, c = t & 15;
  col[(c << 14) | i] = v;
  if (labels[i] != c)
    atomicAdd(&h1[(c << 16) + (ordkey(v) >> BSH)], 1u);
}

// ---- positives: two-level reservation collect (64 blocks; <=64 atomics/addr) ----
// pcnt ends holding the per-class positive count P (used downstream as counts).
__global__ void k_posc(const float* __restrict__ scores, const int* __restrict__ labels,
                       unsigned* __restrict__ pcnt, unsigned long long* __restrict__ ppk) {
  __shared__ unsigned lc[NCLS];
  __shared__ unsigned base[NCLS];
  int tid = threadIdx.x;
  if (tid < NCLS) lc[tid] = 0;
  __syncthreads();
  int i = blockIdx.x * 256 + tid;   // 0..16383
  int c = labels[i] & 15;
  float v = scores[i * NCLS + c];
  unsigned loc = atomicAdd(&lc[c], 1u);
  __syncthreads();
  if (tid < NCLS) base[tid] = lc[tid] ? atomicAdd(&pcnt[tid], lc[tid]) : 0u;
  __syncthreads();
  ppk[(c << 14) + base[c] + loc] = ((unsigned long long)(~ordkey(v)) << 32) | (unsigned)i;
}

// ---- merged: blocks 0-15 = per-class 64K-bucket exclusive scan (1024 thr);
//      blocks 16-31 = positive rank (1 block/class, 1024 thr) ----
#define PCAP 2048
__global__ __launch_bounds__(1024) void k_mid(
    unsigned* __restrict__ h1, const float* __restrict__ col,
    const unsigned* __restrict__ pcnt, const unsigned long long* __restrict__ ppk,
    float* __restrict__ spos) {
  int b = blockIdx.x;
  int tid = threadIdx.x;
  __shared__ unsigned part[1024];
  __shared__ unsigned long long pk[PCAP];
  if (b < NCLS) {
    // exclusive prefix over NB buckets: 1024 threads x 64 consecutive buckets
    unsigned* h = h1 + ((size_t)b << 16);
    unsigned base = (unsigned)tid << 6;
    unsigned s = 0;
    for (int q = 0; q < 64; ++q) s += h[base + q];
    part[tid] = s;
    __syncthreads();
    for (int off = 1; off < 1024; off <<= 1) {
      unsigned v = (tid >= off) ? part[tid - off] : 0u;
      __syncthreads();
      part[tid] += v;
      __syncthreads();
    }
    unsigned running = part[tid] - s;   // exclusive prefix of this thread's chunk
    for (int q = 0; q < 64; ++q) {
      unsigned tmp = h[base + q];
      h[base + q] = running;
      running += tmp;
    }
  } else {
    // positive rank: keys unique -> count-smaller is permutation-invariant
    int c = b - NCLS;
    unsigned P = pcnt[c];
    const unsigned long long* src = ppk + ((size_t)c << 14);
    if (P <= PCAP) {
      for (unsigned t = tid; t < P; t += 1024) pk[t] = src[t];
      __syncthreads();
      for (unsigned q = tid; q < P; q += 1024) {
        unsigned long long k64 = pk[q];
        unsigned cq = 0;
        for (unsigned t = 0; t < P; ++t) cq += (pk[t] < k64) ? 1u : 0u;
        unsigned i = (unsigned)(k64 & 0xFFFFFFFFu);
        spos[(c << 14) + cq] = col[(c << 14) + (int)i];
      }
    } else {  // safety fallback (won't trigger for this input)
      for (unsigned q = tid; q < P; q += 1024) {
        unsigned long long k64 = src[q];
        unsigned cq = 0;
        for (unsigned t = 0; t < P; ++t) cq += (src[t] < k64) ? 1u : 0u;
        unsigned i = (unsigned)(k64 & 0xFFFFFFFFu);
        spos[(c << 14) + cq] = col[(c << 14) + (int)i];
      }
    }
  }
}

// ---- scatter negatives into bucket-grouped array; h1[b] becomes bucket END ----
__global__ void k_scatter(const float* __restrict__ col, const int* __restrict__ labels,
                          unsigned* __restrict__ h1, unsigned* __restrict__ pack) {
  int t = blockIdx.x * 256 + threadIdx.x;
  int c = t >> 14, i = t & 16383;
  if (labels[i] != c) {
    unsigned k = ordkey(col[t]);
    unsigned p = atomicAdd(&h1[(c << 16) + (k >> BSH)], 1u);
    pack[(c << 14) + p] = (k << 16) | (unsigned)i;   // low16 key + idx: unique stable
  }
}

// ---- final rank (bucket start + count-smaller in bucket) -> sneg by rank ----
__global__ void k_rankfine(const float* __restrict__ col, const int* __restrict__ labels,
                           const unsigned* __restrict__ h1, const unsigned* __restrict__ pack,
                           float* __restrict__ sneg) {
  int t = blockIdx.x * 256 + threadIdx.x;
  int c = t >> 14, i = t & 16383;
  if (labels[i] != c) {
    float v = col[t];
    unsigned k = ordkey(v);
    unsigned b = k >> BSH;
    const unsigned* hb = h1 + ((size_t)c << 16);
    unsigned start = b ? hb[b - 1] : 0u;   // after scatter: hb[x] = end of bucket x
    unsigned end = hb[b];
    unsigned mine = (k << 16) | (unsigned)i;
    const unsigned* pk = pack + (c << 14);
    unsigned cnt = start;
    for (unsigned q = start; q < end; ++q) cnt += (pk[q] < mine) ? 1u : 0u;
    sneg[(c << 14) + (int)cnt] = v;        // cnt = 0-based ascending rank (unique)
  }
}

// ============================================================================
// opt_j monotone non-increasing in ascending rank j (the property the
// reference's quickselect D&C exploits) => anchors every ASTEP ranks bracket
// every intermediate opt. Anchor math is the exact validated serial scan.
// ============================================================================
#define SCAP 2048
#define ASTEP 64
#define ABITS 6

// one thread per anchor, 64-thr blocks, grid (5, NCLS): 320 slots >= T<=257
__global__ void k_anchor(const unsigned* __restrict__ counts, const float* __restrict__ spos,
                         const float* __restrict__ sneg, unsigned* __restrict__ aopt) {
  int c = blockIdx.y;
  int P = (int)counts[c];
  int N = C_ITEMS - P;
  if (P == 0 || N == 0) return;
  int tid = threadIdx.x;
  __shared__ float sp[SCAP];
  int stageN = (P <= SCAP) ? P : 0;
  for (int t = tid; t < stageN; t += 64) sp[t] = spos[(c << 14) + t];
  __syncthreads();
  int ta = blockIdx.x * 64 + tid;
  int T = (N + ASTEP - 1) / ASTEP + 1;      // full anchors + terminal anchor at N-1
  if (ta >= T) return;
  float invP = 1.0f / (float)P;
  float coef = 2.0f / ((float)P * (float)N);
  int j0 = min(ta * ASTEP, N - 1);
  float v = sneg[(c << 14) + j0];
  float a = coef * v;
  float fcnt = (float)(j0 + P + 1);
  float s = 0.0f, best = 0.0f;
  int besti = P;
  if (P <= SCAP) {
    for (int q = P - 1; q >= 0; --q) {
      float spv = sp[q];
      float r = __builtin_amdgcn_rcpf(fcnt);
      float delta = fmaf(invP, r, fmaf(-coef, spv, a));
      s += delta;
      if (s >= best) { best = s; besti = q; }
      fcnt -= 1.0f;
    }
  } else {
    const float* spg = spos + ((size_t)c << 14);
    for (int q = P - 1; q >= 0; --q) {
      float spv = spg[q];
      float r = __builtin_amdgcn_rcpf(fcnt);
      float delta = fmaf(invP, r, fmaf(-coef, spv, a));
      s += delta;
      if (s >= best) { best = s; besti = q; }
      fcnt -= 1.0f;
    }
  }
  aopt[(c << 9) + ta] = (unsigned)(besti + 1);
}

// ---- bracketed per-negative argmax + histogram + minus-side sums ----
#define HCAP 2048
__global__ void k_optB(const unsigned* __restrict__ counts, const float* __restrict__ spos,
                       const float* __restrict__ sneg, const unsigned* __restrict__ aopt,
                       unsigned* __restrict__ hist, double* __restrict__ accS,
                       double* __restrict__ accV) {
  int c = blockIdx.y;
  int P = (int)counts[c];
  int N = C_ITEMS - P;
  if (P == 0 || N == 0) return;
  int tid = threadIdx.x;
  int j0 = blockIdx.x * 256 + tid;
  bool active = (j0 < N);
  __shared__ float sp[SCAP];
  __shared__ unsigned lh[HCAP];
  __shared__ double red[256];
  int stageN = (P <= SCAP) ? P : 0;
  int zn = (P + 2 <= HCAP) ? (P + 2) : 0;
  for (int t = tid; t < stageN; t += 256) sp[t] = spos[(c << 14) + t];
  for (int t = tid; t < zn; t += 256) lh[t] = 0u;
  __syncthreads();
  int opt = P + 1;
  float v = 0.0f;
  if (active) {
    v = sneg[(c << 14) + j0];
    int g = j0 >> ABITS;
    int hiA = (int)aopt[(c << 9) + g];
    if ((j0 & (ASTEP - 1)) == 0) {
      opt = hiA;                      // anchor rank: exact full-scan value
    } else {
      int loA = (int)aopt[(c << 9) + g + 1];
      int hi = min(hiA + 2, P + 1);   // +-2 margin absorbs float near-tie wobble
      int lo = max(loA - 2, 1);
      float invP = 1.0f / (float)P;
      float coef = 2.0f / ((float)P * (float)N);
      float a = coef * v;
      float s = 0.0f, best = 0.0f;
      int bestr = hi;                 // empty suffix (value 0) candidate at r=hi
      float fcnt = (float)(j0 + hi);  // j0+1+k at k=hi-1
      if (P <= SCAP) {
        for (int k = hi - 1; k >= lo; --k) {
          float spv = sp[k - 1];
          float r = __builtin_amdgcn_rcpf(fcnt);
          float delta = fmaf(invP, r, fmaf(-coef, spv, a));
          s += delta;
          if (s >= best) { best = s; bestr = k; }
          fcnt -= 1.0f;
        }
      } else {
        const float* spg = spos + ((size_t)c << 14);
        for (int k = hi - 1; k >= lo; --k) {
          float spv = spg[k - 1];
          float r = __builtin_amdgcn_rcpf(fcnt);
          float delta = fmaf(invP, r, fmaf(-coef, spv, a));
          s += delta;
          if (s >= best) { best = s; bestr = k; }
          fcnt -= 1.0f;
        }
      }
      opt = bestr;
    }
  }
  if (P + 2 <= HCAP) {
    if (active) atomicAdd(&lh[opt], 1u);
    __syncthreads();
    for (int t = tid; t < P + 2; t += 256)
      if (lh[t]) atomicAdd(&hist[c * HSTRIDE + t], lh[t]);
  } else {
    if (active) atomicAdd(&hist[c * HSTRIDE + opt], 1u);
  }
  double cm = active ? (double)(P + 2 - 2 * opt) * (double)v : 0.0;
  double sv = active ? (double)v : 0.0;
  red[tid] = cm; __syncthreads();
  for (int sh = 128; sh > 0; sh >>= 1) { if (tid < sh) red[tid] += red[tid + sh]; __syncthreads(); }
  if (tid == 0) atomicAdd(&accS[c], red[0]);
  __syncthreads();
  red[tid] = sv; __syncthreads();
  for (int sh = 128; sh > 0; sh >>= 1) { if (tid < sh) red[tid] += red[tid + sh]; __syncthreads(); }
  if (tid == 0) atomicAdd(&accV[c], red[0]);
}

// ---- per-class: prefix-sum hist -> r_plus, plus-side sums, loss, final out ----
__global__ void k_fin(const unsigned* __restrict__ counts, const unsigned* __restrict__ hist,
                      const float* __restrict__ spos, const double* __restrict__ accS,
                      const double* __restrict__ accV, double* __restrict__ total,
                      unsigned* __restrict__ done, float* __restrict__ out) {
  int c = blockIdx.x;
  int tid = threadIdx.x;
  int P = (int)counts[c];
  int N = C_ITEMS - P;
  __shared__ unsigned sc[256];
  __shared__ double red[256];
  double lc = 0.0;
  if (P > 0 && N > 0) {
    const unsigned* h = hist + c * HSTRIDE;
    int M = P + 1;
    int L = (M + 255) / 256;
    int o0 = 1 + tid * L;
    int o1 = min(o0 + L, P + 2);
    unsigned part = 0;
    for (int o = o0; o < o1; ++o) part += h[o];
    sc[tid] = part;
    __syncthreads();
    if (tid == 0) {
      unsigned runp = 0;
      for (int t = 0; t < 256; ++t) { unsigned tmp = sc[t]; sc[t] = runp; runp += tmp; }
    }
    __syncthreads();
    unsigned run = sc[tid];
    double a1 = 0.0, a2 = 0.0, a3 = 0.0;
    for (int o = o0; o < o1; ++o) {
      run += h[o];
      if (o <= P) {
        int k0 = o - 1;
        double rp = 1.0 + (double)run;
        double spv = (double)spos[(c << 14) + k0];
        a1 += (double)(k0 + 1) / ((double)k0 + rp);
        a2 += spv * ((double)N + 2.0 - 2.0 * rp);
        a3 += spv;
      }
    }
    red[tid] = a1; __syncthreads();
    for (int s = 128; s > 0; s >>= 1) { if (tid < s) red[tid] += red[tid + s]; __syncthreads(); }
    double r1 = red[0]; __syncthreads();
    red[tid] = a2; __syncthreads();
    for (int s = 128; s > 0; s >>= 1) { if (tid < s) red[tid] += red[tid + s]; __syncthreads(); }
    double r2 = red[0]; __syncthreads();
    red[tid] = a3; __syncthreads();
    for (int s = 128; s > 0; s >>= 1) { if (tid < s) red[tid] += red[tid + s]; __syncthreads(); }
    double r3 = red[0];
    if (tid == 0) {
      double Pd = (double)P, Nd = (double)N;
      double FR  = r2 + accS[c];
      double FRs = Nd * r3 - Pd * accV[c];
      lc = (1.0 - r1 / Pd) + (FR - FRs) / (Pd * Nd);
    }
  }
  if (tid == 0) {
    if (P > 0 && N > 0) atomicAdd(total, lc);
    __threadfence();
    unsigned d = atomicAdd(done, 1u);
    if (d == NCLS - 1) {
      double t = atomicAdd(total, 0.0);  // device-scope RMW: coherent final value
      out[0] = (float)(t / (double)NCLS);
    }
  }
}

extern "C" void kernel_launch(void* const* d_in, const int* in_sizes, int n_in,
                              void* d_out, int out_size, void* d_ws, size_t ws_size,
                              hipStream_t stream) {
  (void)in_sizes; (void)n_in; (void)out_size; (void)ws_size;
  const float* scores = (const float*)d_in[0];
  const int* labels = (const int*)d_in[1];
  float* out = (float*)d_out;
  char* ws = (char*)d_ws;
  float* col      = (float*)(ws + OFF_COL);
  float* spos     = (float*)(ws + OFF_SPOS);
  float* sneg     = (float*)(ws + OFF_SNEG);
  unsigned* pack  = (unsigned*)(ws + OFF_PACK);
  unsigned* hist  = (unsigned*)(ws + OFF_HIST);
  unsigned* done  = (unsigned*)(ws + OFF_CNT);
  double* accS    = (double*)(ws + OFF_ACCS);
  double* accV    = (double*)(ws + OFF_ACCV);
  double* total   = (double*)(ws + OFF_TOT);
  unsigned* pcnt  = (unsigned*)(ws + OFF_PC);   // per-class P counts
  unsigned* h1    = (unsigned*)(ws + OFF_H1);
  unsigned long long* ppk = (unsigned long long*)(ws + OFF_PPK);
  unsigned* aopt  = (unsigned*)(ws + OFF_PPK);  // reused after k_mid consumed ppk

  int zn = (int)(ZERO_BYTES / 4);
  k_zero<<<1024, 256, 0, stream>>>(hist, zn);   // zeroes hist..h1 (contiguous ~5.25 MB)
  k_prep<<<1024, 256, 0, stream>>>(scores, labels, col, h1);
  k_posc<<<64, 256, 0, stream>>>(scores, labels, pcnt, ppk);
  k_mid<<<32, 1024, 0, stream>>>(h1, col, pcnt, ppk, spos);
  k_scatter<<<1024, 256, 0, stream>>>(col, labels, h1, pack);
  k_rankfine<<<1024, 256, 0, stream>>>(col, labels, h1, pack, sneg);
  k_anchor<<<dim3(5, NCLS), 64, 0, stream>>>(pcnt, spos, sneg, aopt);
  k_optB<<<dim3(64, NCLS), 256, 0, stream>>>(pcnt, spos, sneg, aopt, hist, accS, accV);
  k_fin<<<NCLS, 256, 0, stream>>>(pcnt, hist, spos, accS, accV, total, done, out);
}